// Round 2
// baseline (359.940 us; speedup 1.0000x reference)
//
#include <hip/hip_runtime.h>
#include <math.h>

#define BOS_TAG 62
#define EOS_TAG 63
#define LTAGS   64
#define S_LEN   1024

// Exact wave-wide max via DPP butterfly (VALU pipe, avoids ds_swizzle latency).
// DPP ctrl must be an immediate -> template parameter.
template <int CTRL>
__device__ __forceinline__ float dpp_fmax_step(float v) {
  int t = __builtin_amdgcn_update_dpp(__float_as_int(v), __float_as_int(v),
                                      CTRL, 0xf, 0xf, false);
  return fmaxf(v, __int_as_float(t));
}

__device__ __forceinline__ float wave_fmax_all(float v) {
  v = dpp_fmax_step<0x111>(v); // row_shr:1
  v = dpp_fmax_step<0x112>(v); // row_shr:2
  v = dpp_fmax_step<0x114>(v); // row_shr:4
  v = dpp_fmax_step<0x118>(v); // row_shr:8  -> lane 15/31/47/63 hold row maxes
  v = dpp_fmax_step<0x142>(v); // row_bcast15 -> lane31 accumulates rows 0-1
  v = dpp_fmax_step<0x143>(v); // row_bcast31 -> lane63 = max over all 64
  return __int_as_float(__builtin_amdgcn_readlane(__float_as_int(v), 63));
}

// One forward-recursion step:
//   m = max_i alpha[i];  w = exp(alpha - m)   (lane-local)
//   s_j = sum_i w[i] * P[i][j]                (readlane-broadcast dot, P col in regs)
//   alpha[j] = (t < len) ? e_t[j] + m + log(s_j) : alpha[j]
#define CRF_STEP(EV, TT)                                                        \
  do {                                                                          \
    float m_ = wave_fmax_all(alpha);                                            \
    float w_ = __expf(alpha - m_);                                              \
    float a0_ = 0.f, a1_ = 0.f, a2_ = 0.f, a3_ = 0.f;                           \
    _Pragma("unroll")                                                           \
    for (int i_ = 0; i_ < LTAGS; i_ += 4) {                                     \
      float w0_ = __int_as_float(                                               \
          __builtin_amdgcn_readlane(__float_as_int(w_), i_ + 0));               \
      float w1_ = __int_as_float(                                               \
          __builtin_amdgcn_readlane(__float_as_int(w_), i_ + 1));               \
      float w2_ = __int_as_float(                                               \
          __builtin_amdgcn_readlane(__float_as_int(w_), i_ + 2));               \
      float w3_ = __int_as_float(                                               \
          __builtin_amdgcn_readlane(__float_as_int(w_), i_ + 3));               \
      a0_ = fmaf(w0_, p[i_ + 0], a0_);                                          \
      a1_ = fmaf(w1_, p[i_ + 1], a1_);                                          \
      a2_ = fmaf(w2_, p[i_ + 2], a2_);                                          \
      a3_ = fmaf(w3_, p[i_ + 3], a3_);                                          \
    }                                                                           \
    float ssum_ = (a0_ + a1_) + (a2_ + a3_);                                    \
    float na_ = (EV) + m_ + __logf(ssum_);                                      \
    alpha = ((TT) < len) ? na_ : alpha;                                         \
  } while (0)

__global__ __launch_bounds__(64) void crf_fwd_kernel(
    const float* __restrict__ em,    // [B, S, L] fp32
    const int* __restrict__ tags,    // [B, S] int32
    const float* __restrict__ mask,  // [B, S] fp32 (prefix 0/1)
    const float* __restrict__ trans, // [L, L] fp32
    float* __restrict__ partial)     // [B] scratch: scores_b - partition_b
{
  const int b = blockIdx.x;
  const int l = threadIdx.x; // lane 0..63 == state j
  const float* emb = em + (size_t)b * S_LEN * LTAGS;
  const int* tb = tags + (size_t)b * S_LEN;
  const float* mb = mask + (size_t)b * S_LEN;

  // ---- sequence length = sum(mask[b,:])  (mask is an exact 0/1 prefix) ----
  float lenf = 0.f;
  for (int t = l; t < S_LEN; t += 64) lenf += mb[t];
#pragma unroll
  for (int off = 32; off; off >>= 1) lenf += __shfl_xor(lenf, off, 64);
  int len = (int)(lenf + 0.5f);
  if (len < 1) len = 1;
  if (len > S_LEN) len = S_LEN;

  // ---- numerator (gold path score) ----
  float sc = 0.f;
  for (int t = l; t < S_LEN; t += 64) {
    if (t >= 1 && t < len) {
      int cur = tb[t], prev = tb[t - 1];
      sc += emb[(size_t)t * LTAGS + cur] + trans[prev * LTAGS + cur];
    }
  }
#pragma unroll
  for (int off = 32; off; off >>= 1) sc += __shfl_xor(sc, off, 64);
  {
    int t0 = tb[0];
    int tl = tb[len - 1];
    sc += trans[BOS_TAG * LTAGS + t0] + emb[t0] + trans[tl * LTAGS + EOS_TAG];
  }

  // ---- P column j into 64 registers: p[i] = exp(T[i][j]) ----
  // T[:,BOS] = -1e4 -> p == 0 exactly; T[EOS,:] = -1e4 -> p[EOS] == 0 exactly.
  float p[LTAGS];
#pragma unroll
  for (int i = 0; i < LTAGS; ++i) p[i] = __expf(trans[i * LTAGS + l]);

  // ---- alpha0 ----
  float alpha = trans[BOS_TAG * LTAGS + l] + emb[l];

  // ---- forward recursion, 4-step chunks with emission prefetch ----
  float eb0 = emb[(size_t)1 * LTAGS + l];
  float eb1 = emb[(size_t)2 * LTAGS + l];
  float eb2 = emb[(size_t)3 * LTAGS + l];
  float eb3 = emb[(size_t)4 * LTAGS + l];

  int t = 1;
  for (; t + 3 < S_LEN; t += 4) {
    float en0 = 0.f, en1 = 0.f, en2 = 0.f, en3 = 0.f;
    if (t + 4 < S_LEN) en0 = emb[(size_t)(t + 4) * LTAGS + l];
    if (t + 5 < S_LEN) en1 = emb[(size_t)(t + 5) * LTAGS + l];
    if (t + 6 < S_LEN) en2 = emb[(size_t)(t + 6) * LTAGS + l];
    if (t + 7 < S_LEN) en3 = emb[(size_t)(t + 7) * LTAGS + l];

    CRF_STEP(eb0, t);
    CRF_STEP(eb1, t + 1);
    CRF_STEP(eb2, t + 2);
    CRF_STEP(eb3, t + 3);

    eb0 = en0; eb1 = en1; eb2 = en2; eb3 = en3;
  }
  for (; t < S_LEN; ++t) { // tail (<=3 steps)
    float e = emb[(size_t)t * LTAGS + l];
    CRF_STEP(e, t);
  }

  // ---- partition = logsumexp_j(alpha[j] + T[j][EOS]) ----
  float fin = alpha + trans[l * LTAGS + EOS_TAG];
  float mf = wave_fmax_all(fin);
  float ex = __expf(fin - mf); // exp(-1e4-ish - mf) == 0 handles the BOS state
#pragma unroll
  for (int off = 32; off; off >>= 1) ex += __shfl_xor(ex, off, 64);
  float partition = mf + __logf(ex);

  if (l == 0) partial[b] = sc - partition;
}

__global__ __launch_bounds__(64) void crf_reduce_kernel(
    const float* __restrict__ partial, float* __restrict__ out, int B) {
  float s = 0.f;
  for (int i = threadIdx.x; i < B; i += 64) s += partial[i];
#pragma unroll
  for (int off = 32; off; off >>= 1) s += __shfl_xor(s, off, 64);
  if (threadIdx.x == 0) out[0] = -s;
}

extern "C" void kernel_launch(void* const* d_in, const int* in_sizes, int n_in,
                              void* d_out, int out_size, void* d_ws, size_t ws_size,
                              hipStream_t stream) {
  const float* em = (const float*)d_in[0];    // emissions [B,S,L]
  const int* tags = (const int*)d_in[1];      // tags [B,S] (int32 per harness)
  const float* mask = (const float*)d_in[2];  // mask [B,S]
  const float* trans = (const float*)d_in[3]; // transitions [L,L]
  float* out = (float*)d_out;
  float* partial = (float*)d_ws;

  const int B = in_sizes[1] / S_LEN; // B*S / S

  crf_fwd_kernel<<<B, 64, 0, stream>>>(em, tags, mask, trans, partial);
  crf_reduce_kernel<<<1, 64, 0, stream>>>(partial, out, B);
}

// Round 4
// 199.306 us; speedup vs baseline: 1.8060x; 1.8060x over previous
//
#include <hip/hip_runtime.h>
#include <math.h>

#define BOS_TAG 62
#define EOS_TAG 63
#define LTAGS   64
#define S_LEN   1024
#define CHUNK   128
#define NCHUNK  8          // S_LEN / CHUNK
#define NSLOT   15         // 8 fwd + 7 bwd chunk-runs per batch
#define LN2F    0.69314718055994530942f

#if defined(__has_builtin)
#if __has_builtin(__builtin_amdgcn_fdot2)
#define USE_FDOT2 1
#endif
#endif
#ifndef USE_FDOT2
#define USE_FDOT2 0
#endif

typedef __fp16 half2_t __attribute__((ext_vector_type(2)));

template <int CTRL>
__device__ __forceinline__ int dpp_mov(int v) {
  return __builtin_amdgcn_update_dpp(v, v, CTRL, 0xf, 0xf, false);
}
template <int CTRL>
__device__ __forceinline__ float dpp_fmax_step(float v) {
  return fmaxf(v, __int_as_float(dpp_mov<CTRL>(__float_as_int(v))));
}
// Exact wave-wide max, broadcast to all lanes (VALU DPP tree + readlane->SGPR).
__device__ __forceinline__ float wave_fmax_all(float v) {
  v = dpp_fmax_step<0x111>(v); // row_shr:1
  v = dpp_fmax_step<0x112>(v); // row_shr:2
  v = dpp_fmax_step<0x114>(v); // row_shr:4
  v = dpp_fmax_step<0x118>(v); // row_shr:8
  v = dpp_fmax_step<0x142>(v); // row_bcast15
  v = dpp_fmax_step<0x143>(v); // row_bcast31
  return __int_as_float(__builtin_amdgcn_readlane(__float_as_int(v), 63));
}
__device__ __forceinline__ float wave_sum(float v) {
#pragma unroll
  for (int off = 32; off; off >>= 1) v += __shfl_xor(v, off, 64);
  return v;
}

// ---- 64-wide broadcast dot: s_lane = sum_i x_i * P.v[i] -----------------
#if USE_FDOT2
struct PMat { half2_t v[32]; };
__device__ __forceinline__ void pmat_set(PMat& P, int i, float q0, float q1) {
  half2_t h; h[0] = (__fp16)q0; h[1] = (__fp16)q1;
  P.v[i] = h;
}
__device__ __forceinline__ float dot64(const PMat& P, float x) {
  // pack (x_j, x_{j^1}) so even lanes hold consecutive pairs
  int xo = dpp_mov<0xB1>(__float_as_int(x)); // quad_perm [1,0,3,2]
  half2_t xp = __builtin_amdgcn_cvt_pkrtz(x, __int_as_float(xo));
  int xpi = __builtin_bit_cast(int, xp);
  float a0 = 0.f, a1 = 0.f, a2 = 0.f, a3 = 0.f;
#pragma unroll
  for (int i = 0; i < 32; i += 4) {
    int s0 = __builtin_amdgcn_readlane(xpi, 2 * (i + 0));
    int s1 = __builtin_amdgcn_readlane(xpi, 2 * (i + 1));
    int s2 = __builtin_amdgcn_readlane(xpi, 2 * (i + 2));
    int s3 = __builtin_amdgcn_readlane(xpi, 2 * (i + 3));
    a0 = __builtin_amdgcn_fdot2(P.v[i + 0], __builtin_bit_cast(half2_t, s0), a0, false);
    a1 = __builtin_amdgcn_fdot2(P.v[i + 1], __builtin_bit_cast(half2_t, s1), a1, false);
    a2 = __builtin_amdgcn_fdot2(P.v[i + 2], __builtin_bit_cast(half2_t, s2), a2, false);
    a3 = __builtin_amdgcn_fdot2(P.v[i + 3], __builtin_bit_cast(half2_t, s3), a3, false);
  }
  return (a0 + a1) + (a2 + a3);
}
#else
struct PMat { float v[LTAGS]; };
__device__ __forceinline__ void pmat_set(PMat& P, int i, float q0, float q1) {
  P.v[2 * i] = q0; P.v[2 * i + 1] = q1;
}
__device__ __forceinline__ float dot64(const PMat& P, float x) {
  int xi = __float_as_int(x);
  float a0 = 0.f, a1 = 0.f, a2 = 0.f, a3 = 0.f;
#pragma unroll
  for (int i = 0; i < LTAGS; i += 4) {
    a0 = fmaf(__int_as_float(__builtin_amdgcn_readlane(xi, i + 0)), P.v[i + 0], a0);
    a1 = fmaf(__int_as_float(__builtin_amdgcn_readlane(xi, i + 1)), P.v[i + 1], a1);
    a2 = fmaf(__int_as_float(__builtin_amdgcn_readlane(xi, i + 2)), P.v[i + 2], a2);
    a3 = fmaf(__int_as_float(__builtin_amdgcn_readlane(xi, i + 3)), P.v[i + 3], a3);
  }
  return (a0 + a1) + (a2 + a3);
}
#endif

// exponent-only renorm: v *= 2^{-e}, sigma += e + 6 (the +6 re-applies the
// 1/64 folded into P). Exact (pure exponent arithmetic, no mantissa change).
__device__ __forceinline__ float renorm_step(float v, int& sigma) {
  float m = wave_fmax_all(v);
  int e = ((__float_as_int(m) >> 23) & 0xff) - 127;
  sigma += e + 6;
  return v * __int_as_float((127 - e) << 23);
}

__device__ __forceinline__ int seq_len(const float* mb, int l) {
  float lenf = 0.f;
  for (int t = l; t < S_LEN; t += 64) lenf += mb[t];
  lenf = wave_sum(lenf);
  int len = (int)(lenf + 0.5f);
  if (len < 1) len = 1;
  if (len > S_LEN) len = S_LEN;
  return len;
}

// ---- chunk kernel: slot<8 -> forward run of chunk k=slot (from alpha0 for
// k==0, from ones otherwise) + chunk score partial; slot>=8 -> backward run
// of chunk k=slot-7 (from ones). Linear-space recursion with P/64 folded.
__global__ __launch_bounds__(64) void crf_chunk_kernel(
    const float* __restrict__ em, const int* __restrict__ tags,
    const float* __restrict__ mask, const float* __restrict__ trans,
    float* __restrict__ Vf, float* __restrict__ Vb,
    float* __restrict__ sf, float* __restrict__ sb,
    float* __restrict__ m0a, float* __restrict__ sca)
{
  const int bid = blockIdx.x;
  const int b = bid / NSLOT;
  const int slot = bid - b * NSLOT;
  const int l = threadIdx.x;
  const float* emb = em + (size_t)b * S_LEN * LTAGS;
  const int len = seq_len(mask + (size_t)b * S_LEN, l);

  if (slot < NCHUNK) {
    const int k = slot;
    const int tstart = k * CHUNK + 1;
    const int tend = (k + 1) * CHUNK < len - 1 ? (k + 1) * CHUNK : len - 1;

    PMat P;  // column l of exp(T)/64: pair (P[2i][l], P[2i+1][l])
#pragma unroll
    for (int i = 0; i < 32; ++i)
      pmat_set(P, i, __expf(trans[(2 * i) * LTAGS + l]) * 0.015625f,
                     __expf(trans[(2 * i + 1) * LTAGS + l]) * 0.015625f);

    float v, m0 = 0.f; int sigma = 0;
    if (k == 0) {
      float a0 = trans[BOS_TAG * LTAGS + l] + emb[l];
      m0 = wave_fmax_all(a0);
      v = __expf(a0 - m0);
    } else {
      v = 1.f;
    }

    // gold-path score over this chunk's steps
    const int* tb = tags + (size_t)b * S_LEN;
    float sc = 0.f;
    for (int tt = tstart + l; tt <= tend; tt += 64) {
      int cur = tb[tt], prev = tb[tt - 1];
      sc += emb[(size_t)tt * LTAGS + cur] + trans[prev * LTAGS + cur];
    }
    sc = wave_sum(sc);
    if (k == 0) {
      int t0 = tb[0];
      sc += trans[BOS_TAG * LTAGS + t0] + emb[t0];
    }

    const float* ep = emb + (size_t)tstart * LTAGS + l;
    float eA = (tstart <= tend) ? ep[0] : 0.f;
    float eB = (tstart + 1 <= tend) ? ep[LTAGS] : 0.f;
    for (int t = tstart; t <= tend; ++t) {
      float eC = (t + 2 <= tend) ? ep[2 * LTAGS] : 0.f;
      ep += LTAGS;
      float E = __expf(eA);
      v = dot64(P, v) * E;
      v = renorm_step(v, sigma);
      eA = eB; eB = eC;
    }
    Vf[((size_t)b * NCHUNK + k) * LTAGS + l] = v;
    if (l == 0) {
      sf[b * NCHUNK + k] = (float)sigma;
      sca[b * NCHUNK + k] = sc;
      if (k == 0) m0a[b] = m0;
    }
  } else {
    const int k = slot - NCHUNK + 1; // 1..7
    const int tstart = k * CHUNK + 1;
    const int tend = (k + 1) * CHUNK < len - 1 ? (k + 1) * CHUNK : len - 1;

    PMat P;  // row l of exp(T)/64: pair (P[l][2i], P[l][2i+1])
#pragma unroll
    for (int i = 0; i < 32; ++i)
      pmat_set(P, i, __expf(trans[l * LTAGS + 2 * i]) * 0.015625f,
                     __expf(trans[l * LTAGS + 2 * i + 1]) * 0.015625f);

    float u = 1.f; int sigma = 0;
    const float* ep = emb + (size_t)tend * LTAGS + l;
    float eA = (tend >= tstart) ? ep[0] : 0.f;
    float eB = (tend - 1 >= tstart) ? ep[-LTAGS] : 0.f;
    for (int t = tend; t >= tstart; --t) {
      float eC = (t - 2 >= tstart) ? ep[-2 * LTAGS] : 0.f;
      ep -= LTAGS;
      float E = __expf(eA);
      float w = E * u;           // (E ⊙ u), then u' = P_row · w
      u = dot64(P, w);
      u = renorm_step(u, sigma);
      eA = eB; eB = eC;
    }
    Vb[((size_t)b * NCHUNK + k) * LTAGS + l] = u;
    if (l == 0) sb[b * NCHUNK + k] = (float)sigma;
  }
}

// ---- combine: rank-1 chunk stitching + score assembly, one wave per batch.
__global__ __launch_bounds__(64) void crf_combine_kernel(
    const float* __restrict__ mask, const int* __restrict__ tags,
    const float* __restrict__ trans,
    const float* __restrict__ Vf, const float* __restrict__ Vb,
    const float* __restrict__ sf, const float* __restrict__ sb,
    const float* __restrict__ m0a, const float* __restrict__ sca,
    float* __restrict__ nll)
{
  const int b = blockIdx.x;
  const int l = threadIdx.x;
  const int len = seq_len(mask + (size_t)b * S_LEN, l);
  const int kb = (len >= 2) ? (len - 2) / CHUNK : 0;

  const float* vf = Vf + (size_t)b * NCHUNK * LTAGS;
  const float* vb = Vb + (size_t)b * NCHUNK * LTAGS;
  const float tvec = __expf(trans[l * LTAGS + EOS_TAG]);

  float vf0 = vf[l];
  float lp;
  if (kb == 0) {
    lp = m0a[b] + LN2F * sf[b * NCHUNK] + logf(wave_sum(vf0 * tvec));
  } else {
    lp = m0a[b] + LN2F * (sf[b * NCHUNK] + sb[b * NCHUNK + 1])
       + logf(wave_sum(vf0 * vb[1 * LTAGS + l]));
    for (int k = 1; k < kb; ++k) {
      float vfk = vf[(size_t)k * LTAGS + l];
      lp += LN2F * sb[b * NCHUNK + k + 1]
          + logf(wave_sum(vfk * vb[(size_t)(k + 1) * LTAGS + l]))
          - logf(wave_sum(vfk));
    }
    float vfb = vf[(size_t)kb * LTAGS + l];
    lp += logf(wave_sum(vfb * tvec)) - logf(wave_sum(vfb));
  }

  float sc = 0.f;
#pragma unroll
  for (int k = 0; k < NCHUNK; ++k) sc += sca[b * NCHUNK + k];
  const int* tb = tags + (size_t)b * S_LEN;
  sc += trans[tb[len - 1] * LTAGS + EOS_TAG];

  if (l == 0) nll[b] = lp - sc;
}

__global__ __launch_bounds__(64) void crf_reduce_kernel(
    const float* __restrict__ nll, float* __restrict__ out, int B) {
  float s = 0.f;
  for (int i = threadIdx.x; i < B; i += 64) s += nll[i];
  s = wave_sum(s);
  if (threadIdx.x == 0) out[0] = s; // sum(partition - score) == -sum(score - partition)
}

// ---- fallback: monolithic per-batch forward (linear space), used only if
// d_ws is too small for the chunked layout.
__global__ __launch_bounds__(64) void crf_mono_kernel(
    const float* __restrict__ em, const int* __restrict__ tags,
    const float* __restrict__ mask, const float* __restrict__ trans,
    float* __restrict__ partial)
{
  const int b = blockIdx.x;
  const int l = threadIdx.x;
  const float* emb = em + (size_t)b * S_LEN * LTAGS;
  const int len = seq_len(mask + (size_t)b * S_LEN, l);

  PMat P;
#pragma unroll
  for (int i = 0; i < 32; ++i)
    pmat_set(P, i, __expf(trans[(2 * i) * LTAGS + l]) * 0.015625f,
                   __expf(trans[(2 * i + 1) * LTAGS + l]) * 0.015625f);

  const int* tb = tags + (size_t)b * S_LEN;
  float sc = 0.f;
  for (int tt = 1 + l; tt <= len - 1; tt += 64) {
    int cur = tb[tt], prev = tb[tt - 1];
    sc += emb[(size_t)tt * LTAGS + cur] + trans[prev * LTAGS + cur];
  }
  sc = wave_sum(sc);
  int t0 = tb[0];
  sc += trans[BOS_TAG * LTAGS + t0] + emb[t0] + trans[tb[len - 1] * LTAGS + EOS_TAG];

  float a0 = trans[BOS_TAG * LTAGS + l] + emb[l];
  float m0 = wave_fmax_all(a0);
  float v = __expf(a0 - m0);
  int sigma = 0;
  for (int t = 1; t <= len - 1; ++t) {
    float E = __expf(emb[(size_t)t * LTAGS + l]);
    v = dot64(P, v) * E;
    v = renorm_step(v, sigma);
  }
  float tvec = __expf(trans[l * LTAGS + EOS_TAG]);
  float lp = m0 + LN2F * (float)sigma + logf(wave_sum(v * tvec));
  if (l == 0) partial[b] = lp - sc;
}

extern "C" void kernel_launch(void* const* d_in, const int* in_sizes, int n_in,
                              void* d_out, int out_size, void* d_ws, size_t ws_size,
                              hipStream_t stream) {
  const float* em = (const float*)d_in[0];
  const int* tags = (const int*)d_in[1];
  const float* mask = (const float*)d_in[2];
  const float* trans = (const float*)d_in[3];
  float* out = (float*)d_out;

  const int B = in_sizes[1] / S_LEN;

  const size_t nV = (size_t)B * NCHUNK * LTAGS;
  const size_t needFloats = 2 * nV + 3 * (size_t)B * NCHUNK + 2 * (size_t)B;
  if (ws_size >= needFloats * sizeof(float)) {
    float* Vf  = (float*)d_ws;
    float* Vb  = Vf + nV;
    float* sf  = Vb + nV;
    float* sb  = sf + (size_t)B * NCHUNK;
    float* sca = sb + (size_t)B * NCHUNK;
    float* m0a = sca + (size_t)B * NCHUNK;
    float* nll = m0a + B;

    crf_chunk_kernel<<<B * NSLOT, 64, 0, stream>>>(em, tags, mask, trans,
                                                   Vf, Vb, sf, sb, m0a, sca);
    crf_combine_kernel<<<B, 64, 0, stream>>>(mask, tags, trans, Vf, Vb,
                                             sf, sb, m0a, sca, nll);
    crf_reduce_kernel<<<1, 64, 0, stream>>>(nll, out, B);
  } else {
    float* partial = (float*)d_ws;
    crf_mono_kernel<<<B, 64, 0, stream>>>(em, tags, mask, trans, partial);
    crf_reduce_kernel<<<1, 64, 0, stream>>>(partial, out, B);
  }
}